// Round 4
// baseline (504.010 us; speedup 1.0000x reference)
//
#include <hip/hip_runtime.h>
#include <math.h>

#define DIM   256
#define NHEAD 8
#define HD    32
#define SEQ   1024
#define BATCH 4
#define ROWS  (BATCH * SEQ)       // 4096 per side
#define ROWS2 (2 * ROWS)          // 8192 (src+tgt batched)
#define FFND  1024
#define QKVN  768
#define ATT_SCALE 0.17677669529663687f  // 32^-0.5

typedef __attribute__((ext_vector_type(8))) short   bf16x8;
typedef __attribute__((ext_vector_type(4))) float   f32x4;

__device__ __forceinline__ unsigned short f2bf(float x) {
    unsigned u = __float_as_uint(x);
    unsigned r = (u + 0x7fffu + ((u >> 16) & 1u)) >> 16;   // RNE
    return (unsigned short)r;
}

// async global->LDS, 16 B per lane. LDS dest = wave-uniform base + lane*16.
typedef const __attribute__((address_space(1))) unsigned int* glds_gp;
typedef __attribute__((address_space(3))) unsigned int*       glds_lp;
__device__ __forceinline__ void glds16(const void* g, void* l) {
    __builtin_amdgcn_global_load_lds((glds_gp)g, (glds_lp)l, 16, 0, 0);
}

// ---------------------------------------------------------------- LayerNorm
__global__ __launch_bounds__(256) void ln_kernel(
        const float* __restrict__ x, const float* __restrict__ g,
        const float* __restrict__ b, unsigned short* __restrict__ y) {
    const int wid  = threadIdx.x >> 6;
    const int lane = threadIdx.x & 63;
    const int row  = blockIdx.x * 4 + wid;
    float4 xv = ((const float4*)(x + (size_t)row * DIM))[lane];
    float s = xv.x + xv.y + xv.z + xv.w;
    #pragma unroll
    for (int off = 32; off >= 1; off >>= 1) s += __shfl_xor(s, off, 64);
    const float mu = s * (1.0f / DIM);
    const float dx = xv.x - mu, dy = xv.y - mu, dz = xv.z - mu, dw = xv.w - mu;
    float sq = dx * dx + dy * dy + dz * dz + dw * dw;
    #pragma unroll
    for (int off = 32; off >= 1; off >>= 1) sq += __shfl_xor(sq, off, 64);
    const float rs = rsqrtf(sq * (1.0f / DIM) + 1e-5f);
    const float4 gv = ((const float4*)g)[lane];
    const float4 bv = ((const float4*)b)[lane];
    ushort4 o;
    o.x = f2bf(dx * rs * gv.x + bv.x);
    o.y = f2bf(dy * rs * gv.y + bv.y);
    o.z = f2bf(dz * rs * gv.z + bv.z);
    o.w = f2bf(dw * rs * gv.w + bv.w);
    ((ushort4*)(y + (size_t)row * DIM))[lane] = o;
}

__global__ __launch_bounds__(256) void ln2_kernel(
        const float* __restrict__ x0, const float* __restrict__ x1,
        const float* __restrict__ g, const float* __restrict__ b,
        unsigned short* __restrict__ y) {
    const int wid  = threadIdx.x >> 6;
    const int lane = threadIdx.x & 63;
    const int row  = blockIdx.x * 4 + wid;
    const float* x = (row < ROWS) ? (x0 + (size_t)row * DIM)
                                  : (x1 + (size_t)(row - ROWS) * DIM);
    float4 xv = ((const float4*)x)[lane];
    float s = xv.x + xv.y + xv.z + xv.w;
    #pragma unroll
    for (int off = 32; off >= 1; off >>= 1) s += __shfl_xor(s, off, 64);
    const float mu = s * (1.0f / DIM);
    const float dx = xv.x - mu, dy = xv.y - mu, dz = xv.z - mu, dw = xv.w - mu;
    float sq = dx * dx + dy * dy + dz * dz + dw * dw;
    #pragma unroll
    for (int off = 32; off >= 1; off >>= 1) sq += __shfl_xor(sq, off, 64);
    const float rs = rsqrtf(sq * (1.0f / DIM) + 1e-5f);
    const float4 gv = ((const float4*)g)[lane];
    const float4 bv = ((const float4*)b)[lane];
    ushort4 o;
    o.x = f2bf(dx * rs * gv.x + bv.x);
    o.y = f2bf(dy * rs * gv.y + bv.y);
    o.z = f2bf(dz * rs * gv.z + bv.z);
    o.w = f2bf(dw * rs * gv.w + bv.w);
    ((ushort4*)(y + (size_t)row * DIM))[lane] = o;
}

// ---------------------------------------------------------------- weight cvt
__global__ __launch_bounds__(256) void convert_weights(
        const float* __restrict__ sa_q_w, const float* __restrict__ sa_k_w,
        const float* __restrict__ sa_v_w, const float* __restrict__ ca_q_w,
        const float* __restrict__ ca_k_w, const float* __restrict__ ca_v_w,
        const float* __restrict__ sa_o_w, const float* __restrict__ ca_o_w,
        const float* __restrict__ ffn_w1, const float* __restrict__ ffn_w2,
        const float* __restrict__ sa_q_b, const float* __restrict__ sa_k_b,
        const float* __restrict__ sa_v_b, const float* __restrict__ ca_q_b,
        const float* __restrict__ ca_k_b, const float* __restrict__ ca_v_b,
        unsigned short* __restrict__ sa_qkv_wt, unsigned short* __restrict__ ca_qkv_wt,
        unsigned short* __restrict__ sa_o_wt,   unsigned short* __restrict__ ca_o_wt,
        unsigned short* __restrict__ ffn1_wt,   unsigned short* __restrict__ ffn2_wt,
        float* __restrict__ sa_qkv_bias, float* __restrict__ ca_qkv_bias) {
    int gid = blockIdx.x * 256 + threadIdx.x;
    if (gid < 196608) {                      // sa qkv wt: [768][256]
        int n = gid >> 8, k = gid & 255, nn = n & 255;
        const float* w = (n < 256) ? sa_q_w : (n < 512) ? sa_k_w : sa_v_w;
        sa_qkv_wt[gid] = f2bf(w[k * 256 + nn]);
        return;
    }
    gid -= 196608;
    if (gid < 196608) {                      // ca qkv wt
        int n = gid >> 8, k = gid & 255, nn = n & 255;
        const float* w = (n < 256) ? ca_q_w : (n < 512) ? ca_k_w : ca_v_w;
        ca_qkv_wt[gid] = f2bf(w[k * 256 + nn]);
        return;
    }
    gid -= 196608;
    if (gid < 65536) { int n = gid >> 8, k = gid & 255; sa_o_wt[gid] = f2bf(sa_o_w[k * 256 + n]); return; }
    gid -= 65536;
    if (gid < 65536) { int n = gid >> 8, k = gid & 255; ca_o_wt[gid] = f2bf(ca_o_w[k * 256 + n]); return; }
    gid -= 65536;
    if (gid < 262144) { int n = gid >> 8,  k = gid & 255;  ffn1_wt[gid] = f2bf(ffn_w1[k * 1024 + n]); return; }
    gid -= 262144;
    if (gid < 262144) { int n = gid >> 10, k = gid & 1023; ffn2_wt[gid] = f2bf(ffn_w2[k * 256 + n]);  return; }
    gid -= 262144;
    if (gid < 768) {
        sa_qkv_bias[gid] = (gid < 256) ? sa_q_b[gid] : (gid < 512) ? sa_k_b[gid - 256] : sa_v_b[gid - 512];
        return;
    }
    gid -= 768;
    if (gid < 768) {
        ca_qkv_bias[gid] = (gid < 256) ? ca_q_b[gid] : (gid < 512) ? ca_k_b[gid - 256] : ca_v_b[gid - 512];
    }
}

// ---------------------------------------------------------------- 64x64 GEMM
// kept for N=256 outputs (o-proj, FFN2): full grid coverage.
template <bool GELU, int MODE>
__global__ __launch_bounds__(256) void gemm_bf16(
        const unsigned short* __restrict__ A, const unsigned short* __restrict__ Wt,
        const float* __restrict__ bias,
        const float* __restrict__ res_lo, const float* __restrict__ res_hi,
        float* __restrict__ Cf, unsigned short* __restrict__ Cb,
        unsigned short* __restrict__ vt_g,
        int N, int K, int rsplit) {
    __shared__ unsigned short As[64 * 64];
    __shared__ unsigned short Ws[64 * 64];
    const int t = threadIdx.x;
    const int w = t >> 6, lane = t & 63, quad = lane >> 4, l16 = lane & 15;
    const int wm = w >> 1, wn = w & 1;
    const int m0 = blockIdx.y * 64, n0 = blockIdx.x * 64;
    const int srow = lane >> 3;
    const int schunk = (lane & 7) ^ srow;

    f32x4 acc[2][2];
    #pragma unroll
    for (int i = 0; i < 2; i++)
        #pragma unroll
        for (int j = 0; j < 2; j++)
            acc[i][j] = (f32x4){0.f, 0.f, 0.f, 0.f};

    for (int k0 = 0; k0 < K; k0 += 64) {
        #pragma unroll
        for (int q = 0; q < 2; q++) {
            const int r0 = w * 16 + q * 8;
            glds16(&A [(size_t)(m0 + r0 + srow) * K + k0 + schunk * 8], &As[r0 * 64]);
            glds16(&Wt[(size_t)(n0 + r0 + srow) * K + k0 + schunk * 8], &Ws[r0 * 64]);
        }
        __syncthreads();
        #pragma unroll
        for (int kc = 0; kc < 2; kc++) {
            bf16x8 af[2], bfr[2];
            #pragma unroll
            for (int i = 0; i < 2; i++) {
                const int ra = wm * 32 + i * 16 + l16;
                const int rb = wn * 32 + i * 16 + l16;
                af[i]  = *(const bf16x8*)&As[ra * 64 + (((kc * 4 + quad) ^ (l16 & 7)) * 8)];
                bfr[i] = *(const bf16x8*)&Ws[rb * 64 + (((kc * 4 + quad) ^ (l16 & 7)) * 8)];
            }
            #pragma unroll
            for (int i = 0; i < 2; i++)
                #pragma unroll
                for (int j = 0; j < 2; j++)
                    acc[i][j] = __builtin_amdgcn_mfma_f32_16x16x32_bf16(af[i], bfr[j], acc[i][j], 0, 0, 0);
        }
        __syncthreads();
    }

    const float* res = nullptr;
    if (MODE == 0 && res_lo)
        res = (m0 < rsplit) ? res_lo : (res_hi - (size_t)rsplit * N);

    #pragma unroll
    for (int i = 0; i < 2; i++) {
        #pragma unroll
        for (int j = 0; j < 2; j++) {
            const int n = n0 + wn * 32 + j * 16 + l16;
            const float bv = bias[n];
            #pragma unroll
            for (int r = 0; r < 4; r++) {
                const int m = m0 + wm * 32 + i * 16 + quad * 4 + r;
                float v = acc[i][j][r] + bv;
                if (GELU) v = 0.5f * v * (1.0f + erff(v * 0.70710678118654752f));
                if (MODE == 0) {
                    if (res) v += res[(size_t)m * N + n];
                    Cf[(size_t)m * N + n] = v;
                } else if (MODE == 1) {
                    Cb[(size_t)m * N + n] = f2bf(v);
                } else {
                    if (n0 < 512) {
                        Cb[(size_t)m * 512 + n] = f2bf(v);
                    } else {
                        const int nn = n - 512, h = nn >> 5, d = nn & 31;
                        const int side = m >> 12, bb = (m >> 10) & 3, seq = m & 1023;
                        vt_g[(size_t)(side * 32 + bb * 8 + h) * 32768 + d * 1024 + seq] = f2bf(v);
                    }
                }
            }
        }
    }
}

// ---------------------------------------------------------------- 128x128 GEMM
// m97 pattern: BK=32, 2x2 waves x 64x64/wave, 16 MFMA/k-iter, glds16 staging.
// Rows are 64 B in LDS; swizzle q^(r&3)^((r>>2)&3) -> exact 2-way (free).
template <bool GELU, int MODE>
__global__ __launch_bounds__(256) void gemm128(
        const unsigned short* __restrict__ A, const unsigned short* __restrict__ Wt,
        const float* __restrict__ bias,
        float* __restrict__ Cf, unsigned short* __restrict__ Cb,
        unsigned short* __restrict__ vt_g,
        int N, int K) {
    __shared__ unsigned short As[128 * 32];
    __shared__ unsigned short Ws[128 * 32];
    const int t = threadIdx.x;
    const int w = t >> 6, lane = t & 63, quad = lane >> 4, l16 = lane & 15;
    const int wm = w >> 1, wn = w & 1;
    const int m0 = blockIdx.y * 128, n0 = blockIdx.x * 128;
    const int srow = lane >> 2;                       // 0..15
    const int sc   = lane & 3;
    const int schunk = sc ^ (srow & 3) ^ ((srow >> 2) & 3);
    const int rdswz = (quad ^ (l16 & 3) ^ ((l16 >> 2) & 3)) * 8;

    f32x4 acc[4][4];
    #pragma unroll
    for (int i = 0; i < 4; i++)
        #pragma unroll
        for (int j = 0; j < 4; j++)
            acc[i][j] = (f32x4){0.f, 0.f, 0.f, 0.f};

    for (int k0 = 0; k0 < K; k0 += 32) {
        glds16(&A [(size_t)(m0 + w * 32 + srow) * K + k0 + schunk * 8],      &As[(w * 32) * 32]);
        glds16(&A [(size_t)(m0 + w * 32 + 16 + srow) * K + k0 + schunk * 8], &As[(w * 32 + 16) * 32]);
        glds16(&Wt[(size_t)(n0 + w * 32 + srow) * K + k0 + schunk * 8],      &Ws[(w * 32) * 32]);
        glds16(&Wt[(size_t)(n0 + w * 32 + 16 + srow) * K + k0 + schunk * 8], &Ws[(w * 32 + 16) * 32]);
        __syncthreads();
        bf16x8 af[4], bfr[4];
        #pragma unroll
        for (int i = 0; i < 4; i++) {
            af[i]  = *(const bf16x8*)&As[(wm * 64 + i * 16 + l16) * 32 + rdswz];
            bfr[i] = *(const bf16x8*)&Ws[(wn * 64 + i * 16 + l16) * 32 + rdswz];
        }
        #pragma unroll
        for (int i = 0; i < 4; i++)
            #pragma unroll
            for (int j = 0; j < 4; j++)
                acc[i][j] = __builtin_amdgcn_mfma_f32_16x16x32_bf16(af[i], bfr[j], acc[i][j], 0, 0, 0);
        __syncthreads();
    }

    #pragma unroll
    for (int i = 0; i < 4; i++) {
        #pragma unroll
        for (int j = 0; j < 4; j++) {
            const int n = n0 + wn * 64 + j * 16 + l16;
            const float bv = bias[n];
            #pragma unroll
            for (int r = 0; r < 4; r++) {
                const int m = m0 + wm * 64 + i * 16 + quad * 4 + r;
                float v = acc[i][j][r] + bv;
                if (GELU) v = 0.5f * v * (1.0f + erff(v * 0.70710678118654752f));
                if (MODE == 1) {
                    Cb[(size_t)m * N + n] = f2bf(v);
                } else {                                    // MODE 2: QKV split
                    if (n < 512) {
                        Cb[(size_t)m * 512 + n] = f2bf(v);
                    } else {
                        const int nn = n - 512, h = nn >> 5, d = nn & 31;
                        const int side = m >> 12, bb = (m >> 10) & 3, seq = m & 1023;
                        vt_g[(size_t)(side * 32 + bb * 8 + h) * 32768 + d * 1024 + seq] = f2bf(v);
                    }
                }
            }
        }
    }
}

// ---------------------------------------------------------------- attention
// Single-barrier double-buffered flash attention, static-max softmax.
// K/V in LDS ping-pong (glds issued post-barrier, in flight through compute);
// bias in register ping-pong (no barrier interaction).
template <bool HAS_BIAS>
__global__ __launch_bounds__(256) void attn_mfma(
        const unsigned short* __restrict__ qk, const unsigned short* __restrict__ vt,
        const float* __restrict__ bias_src, const float* __restrict__ bias_tgt,
        unsigned short* __restrict__ AO, int cross) {
    __shared__ unsigned short Kss[2 * 64 * 32];
    __shared__ unsigned short Vts[2 * 32 * 64];
    __shared__ unsigned short Pss[64 * 72];

    const int t = threadIdx.x;
    const int w = t >> 6, lane = t & 63, quad = lane >> 4, l16 = lane & 15;
    const int bh = blockIdx.y;
    const int side = bh >> 5, b = (bh >> 3) & 3, h = bh & 7;
    const int q0 = blockIdx.x * 64;
    const int qbase  = side * ROWS + b * SEQ;
    const int kvside = cross ? (1 - side) : side;
    const int kvbase = kvside * ROWS + b * SEQ;
    const int bhv = kvside * 32 + b * 8 + h;

    const bf16x8 aq = *(const bf16x8*)&qk[(size_t)(qbase + q0 + w * 16 + l16) * 512 + h * HD + quad * 8];

    const float* brow = nullptr;
    if (HAS_BIAS)
        brow = (side ? bias_tgt : bias_src)
             + ((size_t)(b * NHEAD + h) * SEQ + q0 + w * 16) * SEQ;

    // staging lane geometry
    const int krow  = lane >> 2;                     // 0..15
    const int kslot = (lane & 3) ^ (krow & 3) ^ ((krow >> 2) & 3);
    const int vrow  = lane >> 3;                     // 0..7
    const int vslot = (lane & 7) ^ (vrow & 7);
    const int kswz  = (quad ^ (l16 & 3) ^ ((l16 >> 2) & 3)) * 8;

    auto stageKV = [&](int kt, int bufi) {
        glds16(&qk[(size_t)(kvbase + kt * 64 + w * 16 + krow) * 512 + 256 + h * HD + kslot * 8],
               &Kss[bufi * 2048 + (w * 16) * 32]);
        glds16(&vt[(size_t)bhv * 32768 + (size_t)(w * 8 + vrow) * 1024 + kt * 64 + vslot * 8],
               &Vts[bufi * 2048 + (w * 8) * 64]);
    };

    float lsum[4] = {0.f, 0.f, 0.f, 0.f};
    f32x4 o0 = (f32x4){0.f, 0.f, 0.f, 0.f};
    f32x4 o1 = (f32x4){0.f, 0.f, 0.f, 0.f};
    float breg0[16], breg1[16];

    auto loadBias = [&](int kt, float (&d)[16]) {
        #pragma unroll
        for (int st = 0; st < 4; st++)
            #pragma unroll
            for (int r = 0; r < 4; r++)
                d[st * 4 + r] = brow[(size_t)(quad * 4 + r) * SEQ + kt * 64 + st * 16 + l16];
    };

    stageKV(0, 0);
    if (HAS_BIAS) loadBias(0, breg0);

    auto iter = [&](int kt, float (&bcur)[16], float (&bnxt)[16]) {
        const int cb = kt & 1;
        __syncthreads();                       // K/V(kt) + bias(kt) landed
        if (kt < 15) stageKV(kt + 1, cb ^ 1);  // in flight through compute

        f32x4 s[4];
        #pragma unroll
        for (int st = 0; st < 4; st++) {
            const bf16x8 kf = *(const bf16x8*)&Kss[cb * 2048 + (st * 16 + l16) * 32 + kswz];
            f32x4 z = (f32x4){0.f, 0.f, 0.f, 0.f};
            s[st] = __builtin_amdgcn_mfma_f32_16x16x32_bf16(aq, kf, z, 0, 0, 0);
        }
        if (HAS_BIAS && kt < 15) loadBias(kt + 1, bnxt);

        #pragma unroll
        for (int st = 0; st < 4; st++) {
            #pragma unroll
            for (int r = 0; r < 4; r++) {
                float v = s[st][r] * ATT_SCALE;
                if (HAS_BIAS) v += bcur[st * 4 + r];
                const float p = __expf(v);     // static-max: logits bounded
                lsum[r] += p;
                Pss[(w * 16 + quad * 4 + r) * 72 + st * 16 + l16] = f2bf(p);
            }
        }

        #pragma unroll
        for (int c = 0; c < 2; c++) {
            const bf16x8 ap  = *(const bf16x8*)&Pss[(w * 16 + l16) * 72 + c * 32 + quad * 8];
            const int slot = (((c * 4 + quad) ^ (l16 & 7)) * 8);
            const bf16x8 bv0 = *(const bf16x8*)&Vts[cb * 2048 + l16 * 64 + slot];
            const bf16x8 bv1 = *(const bf16x8*)&Vts[cb * 2048 + (16 + l16) * 64 + slot];
            o0 = __builtin_amdgcn_mfma_f32_16x16x32_bf16(ap, bv0, o0, 0, 0, 0);
            o1 = __builtin_amdgcn_mfma_f32_16x16x32_bf16(ap, bv1, o1, 0, 0, 0);
        }
    };

    for (int kt2 = 0; kt2 < 16; kt2 += 2) {
        iter(kt2,     breg0, breg1);
        iter(kt2 + 1, breg1, breg0);
    }

    #pragma unroll
    for (int r = 0; r < 4; r++) {
        float l = lsum[r];
        #pragma unroll
        for (int off = 1; off < 16; off <<= 1) l += __shfl_xor(l, off, 64);
        const float inv = 1.0f / l;
        const size_t orow = (size_t)(qbase + q0 + w * 16 + quad * 4 + r) * DIM + h * HD;
        AO[orow + l16]      = f2bf(o0[r] * inv);
        AO[orow + 16 + l16] = f2bf(o1[r] * inv);
    }
}

// ---------------------------------------------------------------- launcher
extern "C" void kernel_launch(void* const* d_in, const int* in_sizes, int n_in,
                              void* d_out, int out_size, void* d_ws, size_t ws_size,
                              hipStream_t stream) {
    const float* src_feats    = (const float*)d_in[0];
    const float* tgt_feats    = (const float*)d_in[1];
    const float* src_geo_bias = (const float*)d_in[2];
    const float* tgt_geo_bias = (const float*)d_in[3];
    const float* sa_q_w = (const float*)d_in[4];
    const float* sa_q_b = (const float*)d_in[5];
    const float* sa_k_w = (const float*)d_in[6];
    const float* sa_k_b = (const float*)d_in[7];
    const float* sa_v_w = (const float*)d_in[8];
    const float* sa_v_b = (const float*)d_in[9];
    const float* sa_o_w = (const float*)d_in[10];
    const float* sa_o_b = (const float*)d_in[11];
    const float* ca_q_w = (const float*)d_in[12];
    const float* ca_q_b = (const float*)d_in[13];
    const float* ca_k_w = (const float*)d_in[14];
    const float* ca_k_b = (const float*)d_in[15];
    const float* ca_v_w = (const float*)d_in[16];
    const float* ca_v_b = (const float*)d_in[17];
    const float* ca_o_w = (const float*)d_in[18];
    const float* ca_o_b = (const float*)d_in[19];
    const float* ln_sa_g = (const float*)d_in[20];
    const float* ln_sa_b = (const float*)d_in[21];
    const float* ln_ca_g = (const float*)d_in[22];
    const float* ln_ca_b = (const float*)d_in[23];
    const float* ln_ff_g = (const float*)d_in[24];
    const float* ln_ff_b = (const float*)d_in[25];
    const float* ffn_w1  = (const float*)d_in[26];
    const float* ffn_b1  = (const float*)d_in[27];
    const float* ffn_w2  = (const float*)d_in[28];
    const float* ffn_b2  = (const float*)d_in[29];

    float* out = (float*)d_out;                      // [8192][256] fp32

    // ---- workspace carve ----
    char* ws = (char*)d_ws;
    unsigned short* Xn = (unsigned short*)(ws);                  // [0,4M)  [8192][256]
    unsigned short* QK = (unsigned short*)(ws + (4  << 20));     // [4,12M) [8192][512]
    unsigned short* VT = (unsigned short*)(ws + (12 << 20));     // [12,16M)[64][32][1024]
    unsigned short* AO = (unsigned short*)(ws + (16 << 20));     // [16,20M)[8192][256]
    unsigned short* Hh = (unsigned short*)(ws + (4  << 20));     // [4,20M) alias (FFN hidden)
    char* wp = ws + (20 << 20);
    unsigned short* sa_qkv_wt = (unsigned short*)wp;  wp += 768 * 256 * 2;
    unsigned short* ca_qkv_wt = (unsigned short*)wp;  wp += 768 * 256 * 2;
    unsigned short* sa_o_wt   = (unsigned short*)wp;  wp += 256 * 256 * 2;
    unsigned short* ca_o_wt   = (unsigned short*)wp;  wp += 256 * 256 * 2;
    unsigned short* ffn1_wt   = (unsigned short*)wp;  wp += 1024 * 256 * 2;
    unsigned short* ffn2_wt   = (unsigned short*)wp;  wp += 256 * 1024 * 2;
    float* sa_qkv_bias = (float*)wp;  wp += 768 * 4;
    float* ca_qkv_bias = (float*)wp;  wp += 768 * 4;

    const dim3 blk(256);
    const dim3 attn_grid(SEQ / 64, 64);

    convert_weights<<<dim3(4103), blk, 0, stream>>>(
        sa_q_w, sa_k_w, sa_v_w, ca_q_w, ca_k_w, ca_v_w, sa_o_w, ca_o_w,
        ffn_w1, ffn_w2, sa_q_b, sa_k_b, sa_v_b, ca_q_b, ca_k_b, ca_v_b,
        sa_qkv_wt, ca_qkv_wt, sa_o_wt, ca_o_wt, ffn1_wt, ffn2_wt,
        sa_qkv_bias, ca_qkv_bias);

    // ---- 1. geometric self-attention (src+tgt batched) ----
    ln2_kernel<<<dim3(ROWS2 / 4), blk, 0, stream>>>(src_feats, tgt_feats, ln_sa_g, ln_sa_b, Xn);
    gemm128<false, 2><<<dim3(QKVN / 128, ROWS2 / 128), blk, 0, stream>>>(
        Xn, sa_qkv_wt, sa_qkv_bias, nullptr, QK, VT, QKVN, DIM);
    attn_mfma<true><<<attn_grid, blk, 0, stream>>>(QK, VT, src_geo_bias, tgt_geo_bias, AO, 0);
    gemm_bf16<false, 0><<<dim3(DIM / 64, ROWS2 / 64), blk, 0, stream>>>(
        AO, sa_o_wt, sa_o_b, src_feats, tgt_feats, out, nullptr, nullptr, DIM, DIM, ROWS);

    // ---- 2. cross-attention ----
    ln_kernel<<<dim3(ROWS2 / 4), blk, 0, stream>>>(out, ln_ca_g, ln_ca_b, Xn);
    gemm128<false, 2><<<dim3(QKVN / 128, ROWS2 / 128), blk, 0, stream>>>(
        Xn, ca_qkv_wt, ca_qkv_bias, nullptr, QK, VT, QKVN, DIM);
    attn_mfma<false><<<attn_grid, blk, 0, stream>>>(QK, VT, nullptr, nullptr, AO, 1);
    gemm_bf16<false, 0><<<dim3(DIM / 64, ROWS2 / 64), blk, 0, stream>>>(
        AO, ca_o_wt, ca_o_b, out, out + (size_t)ROWS * DIM, out, nullptr, nullptr, DIM, DIM, ROWS);

    // ---- 3. FFN ----
    ln_kernel<<<dim3(ROWS2 / 4), blk, 0, stream>>>(out, ln_ff_g, ln_ff_b, Xn);
    gemm128<true, 1><<<dim3(FFND / 128, ROWS2 / 128), blk, 0, stream>>>(
        Xn, ffn1_wt, ffn_b1, nullptr, Hh, nullptr, FFND, DIM);
    gemm_bf16<false, 0><<<dim3(DIM / 64, ROWS2 / 64), blk, 0, stream>>>(
        Hh, ffn2_wt, ffn_b2, out, out + (size_t)ROWS * DIM, out, nullptr, nullptr, DIM, FFND, ROWS);
}

// Round 5
// 462.530 us; speedup vs baseline: 1.0897x; 1.0897x over previous
//
#include <hip/hip_runtime.h>
#include <math.h>

#define DIM   256
#define NHEAD 8
#define HD    32
#define SEQ   1024
#define BATCH 4
#define ROWS  (BATCH * SEQ)       // 4096 per side
#define ROWS2 (2 * ROWS)          // 8192 (src+tgt batched)
#define FFND  1024
#define QKVN  768
#define ATT_SCALE 0.17677669529663687f  // 32^-0.5

typedef __attribute__((ext_vector_type(8))) short   bf16x8;
typedef __attribute__((ext_vector_type(4))) float   f32x4;

__device__ __forceinline__ unsigned short f2bf(float x) {
    unsigned u = __float_as_uint(x);
    unsigned r = (u + 0x7fffu + ((u >> 16) & 1u)) >> 16;   // RNE
    return (unsigned short)r;
}

// async global->LDS, 16 B per lane. LDS dest = wave-uniform base + lane*16.
typedef const __attribute__((address_space(1))) unsigned int* glds_gp;
typedef __attribute__((address_space(3))) unsigned int*       glds_lp;
__device__ __forceinline__ void glds16(const void* g, void* l) {
    __builtin_amdgcn_global_load_lds((glds_gp)g, (glds_lp)l, 16, 0, 0);
}

// s_waitcnt vmcnt(N) only (expcnt=7, lgkmcnt=15 untouched). gfx9 encoding:
// vmcnt[3:0]=imm[3:0], vmcnt[5:4]=imm[15:14].
#define WAITVM(N) __builtin_amdgcn_s_waitcnt(0x0F70 | ((N) & 0xF) | (((N) >> 4) << 14))

// ---------------------------------------------------------------- LayerNorm
__global__ __launch_bounds__(256) void ln_kernel(
        const float* __restrict__ x, const float* __restrict__ g,
        const float* __restrict__ b, unsigned short* __restrict__ y) {
    const int wid  = threadIdx.x >> 6;
    const int lane = threadIdx.x & 63;
    const int row  = blockIdx.x * 4 + wid;
    float4 xv = ((const float4*)(x + (size_t)row * DIM))[lane];
    float s = xv.x + xv.y + xv.z + xv.w;
    #pragma unroll
    for (int off = 32; off >= 1; off >>= 1) s += __shfl_xor(s, off, 64);
    const float mu = s * (1.0f / DIM);
    const float dx = xv.x - mu, dy = xv.y - mu, dz = xv.z - mu, dw = xv.w - mu;
    float sq = dx * dx + dy * dy + dz * dz + dw * dw;
    #pragma unroll
    for (int off = 32; off >= 1; off >>= 1) sq += __shfl_xor(sq, off, 64);
    const float rs = rsqrtf(sq * (1.0f / DIM) + 1e-5f);
    const float4 gv = ((const float4*)g)[lane];
    const float4 bv = ((const float4*)b)[lane];
    ushort4 o;
    o.x = f2bf(dx * rs * gv.x + bv.x);
    o.y = f2bf(dy * rs * gv.y + bv.y);
    o.z = f2bf(dz * rs * gv.z + bv.z);
    o.w = f2bf(dw * rs * gv.w + bv.w);
    ((ushort4*)(y + (size_t)row * DIM))[lane] = o;
}

__global__ __launch_bounds__(256) void ln2_kernel(
        const float* __restrict__ x0, const float* __restrict__ x1,
        const float* __restrict__ g, const float* __restrict__ b,
        unsigned short* __restrict__ y) {
    const int wid  = threadIdx.x >> 6;
    const int lane = threadIdx.x & 63;
    const int row  = blockIdx.x * 4 + wid;
    const float* x = (row < ROWS) ? (x0 + (size_t)row * DIM)
                                  : (x1 + (size_t)(row - ROWS) * DIM);
    float4 xv = ((const float4*)x)[lane];
    float s = xv.x + xv.y + xv.z + xv.w;
    #pragma unroll
    for (int off = 32; off >= 1; off >>= 1) s += __shfl_xor(s, off, 64);
    const float mu = s * (1.0f / DIM);
    const float dx = xv.x - mu, dy = xv.y - mu, dz = xv.z - mu, dw = xv.w - mu;
    float sq = dx * dx + dy * dy + dz * dz + dw * dw;
    #pragma unroll
    for (int off = 32; off >= 1; off >>= 1) sq += __shfl_xor(sq, off, 64);
    const float rs = rsqrtf(sq * (1.0f / DIM) + 1e-5f);
    const float4 gv = ((const float4*)g)[lane];
    const float4 bv = ((const float4*)b)[lane];
    ushort4 o;
    o.x = f2bf(dx * rs * gv.x + bv.x);
    o.y = f2bf(dy * rs * gv.y + bv.y);
    o.z = f2bf(dz * rs * gv.z + bv.z);
    o.w = f2bf(dw * rs * gv.w + bv.w);
    ((ushort4*)(y + (size_t)row * DIM))[lane] = o;
}

// ---------------------------------------------------------------- weight cvt
// LDS-tiled transpose-convert: coalesced fp32 reads, coalesced bf16 writes.
// 256 tile-blocks of 64x64 + 2 bias blocks.
__global__ __launch_bounds__(256) void convert_weights(
        const float* __restrict__ sa_q_w, const float* __restrict__ sa_k_w,
        const float* __restrict__ sa_v_w, const float* __restrict__ ca_q_w,
        const float* __restrict__ ca_k_w, const float* __restrict__ ca_v_w,
        const float* __restrict__ sa_o_w, const float* __restrict__ ca_o_w,
        const float* __restrict__ ffn_w1, const float* __restrict__ ffn_w2,
        const float* __restrict__ sa_q_b, const float* __restrict__ sa_k_b,
        const float* __restrict__ sa_v_b, const float* __restrict__ ca_q_b,
        const float* __restrict__ ca_k_b, const float* __restrict__ ca_v_b,
        unsigned short* __restrict__ sa_qkv_wt, unsigned short* __restrict__ ca_qkv_wt,
        unsigned short* __restrict__ sa_o_wt,   unsigned short* __restrict__ ca_o_wt,
        unsigned short* __restrict__ ffn1_wt,   unsigned short* __restrict__ ffn2_wt,
        float* __restrict__ sa_qkv_bias, float* __restrict__ ca_qkv_bias) {
    const int bid = blockIdx.x, t = threadIdx.x;
    if (bid >= 256) {
        const float* qb = (bid == 256) ? sa_q_b : ca_q_b;
        const float* kb = (bid == 256) ? sa_k_b : ca_k_b;
        const float* vb = (bid == 256) ? sa_v_b : ca_v_b;
        float* ob = (bid == 256) ? sa_qkv_bias : ca_qkv_bias;
        for (int e = t; e < 768; e += 256)
            ob[e] = (e < 256) ? qb[e] : (e < 512) ? kb[e - 256] : vb[e - 512];
        return;
    }
    const float* src; unsigned short* dst;
    int Ns, Kd, sk, sn, dn;
    if (bid < 96) {                               // qkv: 48 tiles each (4k x 12n)
        int q = bid; const bool sa = q < 48; if (!sa) q -= 48;
        const int kt = q & 3, nt = q >> 2, sub = nt >> 2;
        src = sa ? (sub == 0 ? sa_q_w : sub == 1 ? sa_k_w : sa_v_w)
                 : (sub == 0 ? ca_q_w : sub == 1 ? ca_k_w : ca_v_w);
        dst = sa ? sa_qkv_wt : ca_qkv_wt;
        Ns = 256; Kd = 256; sk = kt * 64; sn = (nt & 3) * 64; dn = nt * 64;
    } else if (bid < 128) {                       // o-proj: 16 tiles each
        int q = bid - 96; const bool sa = q < 16; if (!sa) q -= 16;
        const int kt = q & 3, nt = q >> 2;
        src = sa ? sa_o_w : ca_o_w; dst = sa ? sa_o_wt : ca_o_wt;
        Ns = 256; Kd = 256; sk = kt * 64; sn = nt * 64; dn = nt * 64;
    } else if (bid < 192) {                       // ffn1: 4k x 16n
        const int q = bid - 128, kt = q & 3, nt = q >> 2;
        src = ffn_w1; dst = ffn1_wt; Ns = 1024; Kd = 256;
        sk = kt * 64; sn = nt * 64; dn = nt * 64;
    } else {                                      // ffn2: 16k x 4n
        const int q = bid - 192, kt = q & 15, nt = q >> 4;
        src = ffn_w2; dst = ffn2_wt; Ns = 256; Kd = 1024;
        sk = kt * 64; sn = nt * 64; dn = nt * 64;
    }
    __shared__ float T[64][65];
    #pragma unroll
    for (int p = 0; p < 4; p++) {
        const int r = p * 16 + (t >> 4), c = (t & 15) * 4;
        float4 v = *(const float4*)&src[(size_t)(sk + r) * Ns + sn + c];
        T[r][c] = v.x; T[r][c + 1] = v.y; T[r][c + 2] = v.z; T[r][c + 3] = v.w;
    }
    __syncthreads();
    #pragma unroll
    for (int p = 0; p < 2; p++) {
        const int nr = p * 32 + (t >> 3), kc = (t & 7) * 8;
        bf16x8 o;
        #pragma unroll
        for (int e = 0; e < 8; e++) o[e] = (short)f2bf(T[kc + e][nr]);
        *(bf16x8*)&dst[(size_t)(dn + nr) * Kd + sk + kc] = o;
    }
}

// ---------------------------------------------------------------- bf16 GEMM
// C = act(A[M,K] @ Wt[N,K]^T + bias) (+res). 64x64 tile, BK=64, 4 waves 2x2,
// glds16 staging. Epilogue restages C through LDS for coalesced stores.
// MODE 0: f32 out + residual; 1: bf16 out; 2: QKV split (Q,K -> ld 512;
//         V -> vt_g transposed [bh][hd][seq] via LDS transpose).
template <bool GELU, int MODE>
__global__ __launch_bounds__(256) void gemm_bf16(
        const unsigned short* __restrict__ A, const unsigned short* __restrict__ Wt,
        const float* __restrict__ bias,
        const float* __restrict__ res_lo, const float* __restrict__ res_hi,
        float* __restrict__ Cf, unsigned short* __restrict__ Cb,
        unsigned short* __restrict__ vt_g,
        int N, int K, int rsplit) {
    __shared__ char smem[17408];                      // staging 16K | epi 17K
    unsigned short* As = (unsigned short*)smem;       // [64][64]
    unsigned short* Ws = (unsigned short*)(smem + 8192);
    const int t = threadIdx.x;
    const int w = t >> 6, lane = t & 63, quad = lane >> 4, l16 = lane & 15;
    const int wm = w >> 1, wn = w & 1;
    const int m0 = blockIdx.y * 64, n0 = blockIdx.x * 64;
    const int srow = lane >> 3;
    const int schunk = (lane & 7) ^ srow;

    f32x4 acc[2][2];
    #pragma unroll
    for (int i = 0; i < 2; i++)
        #pragma unroll
        for (int j = 0; j < 2; j++)
            acc[i][j] = (f32x4){0.f, 0.f, 0.f, 0.f};

    for (int k0 = 0; k0 < K; k0 += 64) {
        #pragma unroll
        for (int q = 0; q < 2; q++) {
            const int r0 = w * 16 + q * 8;
            glds16(&A [(size_t)(m0 + r0 + srow) * K + k0 + schunk * 8], &As[r0 * 64]);
            glds16(&Wt[(size_t)(n0 + r0 + srow) * K + k0 + schunk * 8], &Ws[r0 * 64]);
        }
        __syncthreads();
        #pragma unroll
        for (int kc = 0; kc < 2; kc++) {
            bf16x8 af[2], bfr[2];
            #pragma unroll
            for (int i = 0; i < 2; i++) {
                const int ra = wm * 32 + i * 16 + l16;
                const int rb = wn * 32 + i * 16 + l16;
                af[i]  = *(const bf16x8*)&As[ra * 64 + (((kc * 4 + quad) ^ (l16 & 7)) * 8)];
                bfr[i] = *(const bf16x8*)&Ws[rb * 64 + (((kc * 4 + quad) ^ (l16 & 7)) * 8)];
            }
            #pragma unroll
            for (int i = 0; i < 2; i++)
                #pragma unroll
                for (int j = 0; j < 2; j++)
                    acc[i][j] = __builtin_amdgcn_mfma_f32_16x16x32_bf16(af[i], bfr[j], acc[i][j], 0, 0, 0);
        }
        __syncthreads();
    }

    // ---------------- epilogue: LDS restage -> coalesced stores ----------------
    const bool vpart = (MODE == 2) && (n0 >= 512);
    float* Ctf = (float*)smem;                        // [64][68] (MODE 0)
    unsigned short* Ctb = (unsigned short*)smem;      // [64][72] (MODE 1/2)
    #pragma unroll
    for (int i = 0; i < 2; i++) {
        #pragma unroll
        for (int j = 0; j < 2; j++) {
            const int nloc = wn * 32 + j * 16 + l16;
            const float bv = bias[n0 + nloc];
            #pragma unroll
            for (int r = 0; r < 4; r++) {
                const int mloc = wm * 32 + i * 16 + quad * 4 + r;
                float v = acc[i][j][r] + bv;
                if (GELU) v = 0.5f * v * (1.0f + erff(v * 0.70710678118654752f));
                if (MODE == 0)       Ctf[mloc * 68 + nloc] = v;
                else if (!vpart)     Ctb[mloc * 72 + nloc] = f2bf(v);
                else                 Ctb[nloc * 72 + mloc] = f2bf(v);
            }
        }
    }
    __syncthreads();
    if (MODE == 0) {
        const float* res = res_lo ? ((m0 < rsplit) ? res_lo : (res_hi - (size_t)rsplit * N))
                                  : nullptr;
        #pragma unroll
        for (int p = 0; p < 4; p++) {
            const int row = p * 16 + (t >> 4), c4 = (t & 15) * 4;
            float4 v = *(float4*)&Ctf[row * 68 + c4];
            const size_t go = (size_t)(m0 + row) * N + n0 + c4;
            if (res) {
                float4 rr = *(const float4*)&res[go];
                v.x += rr.x; v.y += rr.y; v.z += rr.z; v.w += rr.w;
            }
            *(float4*)&Cf[go] = v;
        }
    } else if (!vpart) {
        const int ldo = (MODE == 2) ? 512 : N;
        #pragma unroll
        for (int p = 0; p < 2; p++) {
            const int row = p * 32 + (t >> 3), ch = (t & 7) * 8;
            *(bf16x8*)&Cb[(size_t)(m0 + row) * ldo + n0 + ch] = *(bf16x8*)&Ctb[row * 72 + ch];
        }
    } else {
        const int side = m0 >> 12, bb = (m0 >> 10) & 3, seq0 = m0 & 1023;
        const int h0 = (n0 - 512) >> 5;
        #pragma unroll
        for (int p = 0; p < 2; p++) {
            const int nl = p * 32 + (t >> 3), ch = (t & 7) * 8;
            const int h = h0 + (nl >> 5), d = nl & 31;
            *(bf16x8*)&vt_g[(size_t)(side * 32 + bb * 8 + h) * 32768 + d * 1024 + seq0 + ch]
                = *(bf16x8*)&Ctb[nl * 72 + ch];
        }
    }
}

// ---------------------------------------------------------------- attention
// Persistent-pipeline flash attention (static-max softmax). Raw s_barrier +
// explicit vmcnt(N>0): bias(kt+1) glds stays in flight ACROSS the barrier,
// consumed a full iteration after issue. K/V block-shared LDS dbuf; bias
// wave-private LDS dbuf. All staging via global_load_lds (program-ordered).
template <bool HAS_BIAS>
__global__ __launch_bounds__(256) void attn_mfma(
        const unsigned short* __restrict__ qk, const unsigned short* __restrict__ vt,
        const float* __restrict__ bias_src, const float* __restrict__ bias_tgt,
        unsigned short* __restrict__ AO, int cross) {
    __shared__ unsigned short Kss[2 * 64 * 32];
    __shared__ unsigned short Vts[2 * 32 * 64];
    __shared__ unsigned short Pss[64 * 72];
    __shared__ float Bls[HAS_BIAS ? 2 * 4096 : 4];    // [buf][wave][16r][64c]

    const int t = threadIdx.x;
    const int w = t >> 6, lane = t & 63, quad = lane >> 4, l16 = lane & 15;
    const int bh = blockIdx.y;
    const int side = bh >> 5, b = (bh >> 3) & 3, h = bh & 7;
    const int q0 = blockIdx.x * 64;
    const int qbase  = side * ROWS + b * SEQ;
    const int kvside = cross ? (1 - side) : side;
    const int kvbase = kvside * ROWS + b * SEQ;
    const int bhv = kvside * 32 + b * 8 + h;

    const bf16x8 aq = *(const bf16x8*)&qk[(size_t)(qbase + q0 + w * 16 + l16) * 512 + h * HD + quad * 8];

    const float* brow = nullptr;
    if (HAS_BIAS)
        brow = (side ? bias_tgt : bias_src)
             + ((size_t)(b * NHEAD + h) * SEQ + q0 + w * 16) * SEQ;

    const int krow  = lane >> 2;
    const int kslot = (lane & 3) ^ (krow & 3) ^ ((krow >> 2) & 3);
    const int vrow  = lane >> 3;
    const int vslot = (lane & 7) ^ (vrow & 7);
    const int kswz  = (quad ^ (l16 & 3) ^ ((l16 >> 2) & 3)) * 8;
    const int brw   = lane >> 4;
    const int bcl   = (lane & 15) * 4;

    auto stageKV = [&](int kt, int buf) {
        glds16(&qk[(size_t)(kvbase + kt * 64 + w * 16 + krow) * 512 + 256 + h * HD + kslot * 8],
               &Kss[buf * 2048 + (w * 16) * 32]);
        glds16(&vt[(size_t)bhv * 32768 + (size_t)(w * 8 + vrow) * 1024 + kt * 64 + vslot * 8],
               &Vts[buf * 2048 + (w * 8) * 64]);
    };
    auto stageBias = [&](int kt, int buf) {
        #pragma unroll
        for (int g = 0; g < 4; g++)
            glds16(&brow[(size_t)(g * 4 + brw) * SEQ + kt * 64 + bcl],
                   &Bls[buf * 4096 + w * 1024 + g * 256]);
    };

    float lsum[4] = {0.f, 0.f, 0.f, 0.f};
    f32x4 o0 = (f32x4){0.f, 0.f, 0.f, 0.f};
    f32x4 o1 = (f32x4){0.f, 0.f, 0.f, 0.f};

    stageKV(0, 0);
    if (HAS_BIAS) stageBias(0, 0);
    WAITVM(HAS_BIAS ? 4 : 0);                 // KV(0) done; bias(0) in flight
    __builtin_amdgcn_s_barrier();

    for (int kt = 0; kt < 16; kt++) {
        const int cb = kt & 1;
        if (kt < 15) {                        // issue next tile immediately
            stageKV(kt + 1, cb ^ 1);
            if (HAS_BIAS) stageBias(kt + 1, cb ^ 1);
        }

        f32x4 s[4];                           // S = Q K^T
        #pragma unroll
        for (int st = 0; st < 4; st++) {
            const bf16x8 kf = *(const bf16x8*)&Kss[cb * 2048 + (st * 16 + l16) * 32 + kswz];
            f32x4 z = (f32x4){0.f, 0.f, 0.f, 0.f};
            s[st] = __builtin_amdgcn_mfma_f32_16x16x32_bf16(aq, kf, z, 0, 0, 0);
        }

        if (HAS_BIAS) {                       // bias(kt) landed (oldest 4)
            if (kt < 15) WAITVM(6); else WAITVM(0);
        }
        const float* bb = HAS_BIAS ? &Bls[cb * 4096 + w * 1024] : nullptr;
        #pragma unroll
        for (int st = 0; st < 4; st++) {
            #pragma unroll
            for (int r = 0; r < 4; r++) {
                float v = s[st][r] * ATT_SCALE;
                if (HAS_BIAS) v += bb[quad * 256 + r * 64 + st * 16 + l16];
                const float p = __expf(v);    // static-max: logits bounded
                lsum[r] += p;
                Pss[(w * 16 + quad * 4 + r) * 72 + st * 16 + l16] = f2bf(p);
            }
        }

        #pragma unroll
        for (int c = 0; c < 2; c++) {         // O += P V
            const bf16x8 ap  = *(const bf16x8*)&Pss[(w * 16 + l16) * 72 + c * 32 + quad * 8];
            const int slot = (((c * 4 + quad) ^ (l16 & 7)) * 8);
            const bf16x8 bv0 = *(const bf16x8*)&Vts[cb * 2048 + l16 * 64 + slot];
            const bf16x8 bv1 = *(const bf16x8*)&Vts[cb * 2048 + (16 + l16) * 64 + slot];
            o0 = __builtin_amdgcn_mfma_f32_16x16x32_bf16(ap, bv0, o0, 0, 0, 0);
            o1 = __builtin_amdgcn_mfma_f32_16x16x32_bf16(ap, bv1, o1, 0, 0, 0);
        }

        if (kt < 15) {
            WAITVM(HAS_BIAS ? 4 : 0);         // KV(kt+1) done; bias(kt+1) stays in flight
            __builtin_amdgcn_s_barrier();
        }
    }

    #pragma unroll
    for (int r = 0; r < 4; r++) {
        float l = lsum[r];
        #pragma unroll
        for (int off = 1; off < 16; off <<= 1) l += __shfl_xor(l, off, 64);
        const float inv = 1.0f / l;
        const size_t orow = (size_t)(qbase + q0 + w * 16 + quad * 4 + r) * DIM + h * HD;
        AO[orow + l16]      = f2bf(o0[r] * inv);
        AO[orow + 16 + l16] = f2bf(o1[r] * inv);
    }
}

// ---------------------------------------------------------------- launcher
extern "C" void kernel_launch(void* const* d_in, const int* in_sizes, int n_in,
                              void* d_out, int out_size, void* d_ws, size_t ws_size,
                              hipStream_t stream) {
    const float* src_feats    = (const float*)d_in[0];
    const float* tgt_feats    = (const float*)d_in[1];
    const float* src_geo_bias = (const float*)d_in[2];
    const float* tgt_geo_bias = (const float*)d_in[3];
    const float* sa_q_w = (const float*)d_in[4];
    const float* sa_q_b = (const float*)d_in[5];
    const float* sa_k_w = (const float*)d_in[6];
    const float* sa_k_b = (const float*)d_in[7];
    const float* sa_v_w = (const float*)d_in[8];
    const float* sa_v_b = (const float*)d_in[9];
    const float* sa_o_w = (const float*)d_in[10];
    const float* sa_o_b = (const float*)d_in[11];
    const float* ca_q_w = (const float*)d_in[12];
    const float* ca_q_b = (const float*)d_in[13];
    const float* ca_k_w = (const float*)d_in[14];
    const float* ca_k_b = (const float*)d_in[15];
    const float* ca_v_w = (const float*)d_in[16];
    const float* ca_v_b = (const float*)d_in[17];
    const float* ca_o_w = (const float*)d_in[18];
    const float* ca_o_b = (const float*)d_in[19];
    const float* ln_sa_g = (const float*)d_in[20];
    const float* ln_sa_b = (const float*)d_in[21];
    const float* ln_ca_g = (const float*)d_in[22];
    const float* ln_ca_b = (const float*)d_in[23];
    const float* ln_ff_g = (const float*)d_in[24];
    const float* ln_ff_b = (const float*)d_in[25];
    const float* ffn_w1  = (const float*)d_in[26];
    const float* ffn_b1  = (const float*)d_in[27];
    const float* ffn_w2  = (const float*)d_in[28];
    const float* ffn_b2  = (const float*)d_in[29];

    float* out = (float*)d_out;                      // [8192][256] fp32

    // ---- workspace carve ----
    char* ws = (char*)d_ws;
    unsigned short* Xn = (unsigned short*)(ws);                  // [0,4M)  [8192][256]
    unsigned short* QK = (unsigned short*)(ws + (4  << 20));     // [4,12M) [8192][512]
    unsigned short* VT = (unsigned short*)(ws + (12 << 20));     // [12,16M)[64][32][1024]
    unsigned short* AO = (unsigned short*)(ws + (16 << 20));     // [16,20M)[8192][256]
    unsigned short* Hh = (unsigned short*)(ws + (4  << 20));     // [4,20M) alias (FFN hidden)
    char* wp = ws + (20 << 20);
    unsigned short* sa_qkv_wt = (unsigned short*)wp;  wp += 768 * 256 * 2;
    unsigned short* ca_qkv_wt = (unsigned short*)wp;  wp += 768 * 256 * 2;
    unsigned short* sa_o_wt   = (unsigned short*)wp;  wp += 256 * 256 * 2;
    unsigned short* ca_o_wt   = (unsigned short*)wp;  wp += 256 * 256 * 2;
    unsigned short* ffn1_wt   = (unsigned short*)wp;  wp += 1024 * 256 * 2;
    unsigned short* ffn2_wt   = (unsigned short*)wp;  wp += 256 * 1024 * 2;
    float* sa_qkv_bias = (float*)wp;  wp += 768 * 4;
    float* ca_qkv_bias = (float*)wp;  wp += 768 * 4;

    const dim3 blk(256);
    const dim3 attn_grid(SEQ / 64, 64);

    convert_weights<<<dim3(258), blk, 0, stream>>>(
        sa_q_w, sa_k_w, sa_v_w, ca_q_w, ca_k_w, ca_v_w, sa_o_w, ca_o_w,
        ffn_w1, ffn_w2, sa_q_b, sa_k_b, sa_v_b, ca_q_b, ca_k_b, ca_v_b,
        sa_qkv_wt, ca_qkv_wt, sa_o_wt, ca_o_wt, ffn1_wt, ffn2_wt,
        sa_qkv_bias, ca_qkv_bias);

    // ---- 1. geometric self-attention (src+tgt batched) ----
    ln2_kernel<<<dim3(ROWS2 / 4), blk, 0, stream>>>(src_feats, tgt_feats, ln_sa_g, ln_sa_b, Xn);
    gemm_bf16<false, 2><<<dim3(QKVN / 64, ROWS2 / 64), blk, 0, stream>>>(
        Xn, sa_qkv_wt, sa_qkv_bias, nullptr, nullptr, nullptr, QK, VT, QKVN, DIM, ROWS);
    attn_mfma<true><<<attn_grid, blk, 0, stream>>>(QK, VT, src_geo_bias, tgt_geo_bias, AO, 0);
    gemm_bf16<false, 0><<<dim3(DIM / 64, ROWS2 / 64), blk, 0, stream>>>(
        AO, sa_o_wt, sa_o_b, src_feats, tgt_feats, out, nullptr, nullptr, DIM, DIM, ROWS);

    // ---- 2. cross-attention ----
    ln_kernel<<<dim3(ROWS2 / 4), blk, 0, stream>>>(out, ln_ca_g, ln_ca_b, Xn);
    gemm_bf16<false, 2><<<dim3(QKVN / 64, ROWS2 / 64), blk, 0, stream>>>(
        Xn, ca_qkv_wt, ca_qkv_bias, nullptr, nullptr, nullptr, QK, VT, QKVN, DIM, ROWS);
    attn_mfma<false><<<attn_grid, blk, 0, stream>>>(QK, VT, nullptr, nullptr, AO, 1);
    gemm_bf16<false, 0><<<dim3(DIM / 64, ROWS2 / 64), blk, 0, stream>>>(
        AO, ca_o_wt, ca_o_b, out, out + (size_t)ROWS * DIM, out, nullptr, nullptr, DIM, DIM, ROWS);

    // ---- 3. FFN ----
    ln_kernel<<<dim3(ROWS2 / 4), blk, 0, stream>>>(out, ln_ff_g, ln_ff_b, Xn);
    gemm_bf16<true, 1><<<dim3(FFND / 64, ROWS2 / 64), blk, 0, stream>>>(
        Xn, ffn1_wt, ffn_b1, nullptr, nullptr, nullptr, Hh, nullptr, FFND, DIM, ROWS);
    gemm_bf16<false, 0><<<dim3(DIM / 64, ROWS2 / 64), blk, 0, stream>>>(
        Hh, ffn2_wt, ffn_b2, out, out + (size_t)ROWS * DIM, out, nullptr, nullptr, DIM, FFND, ROWS);
}